// Round 2
// baseline (337.969 us; speedup 1.0000x reference)
//
#include <hip/hip_runtime.h>
#include <hip/hip_bf16.h>

typedef __attribute__((ext_vector_type(8))) short short8;
typedef __attribute__((ext_vector_type(4))) float float4v;

#define L_SEQ 768
#define C_IN 384
#define C_OUT 32
#define N_OUT 128

using bf16 = __hip_bfloat16;

static __device__ inline bf16 f2b(float f) { return __float2bfloat16(f); }

// ---------------------------------------------------------------------------
// Stage 1: LayerNorm + left/right projections + Ri = b_out - right @ Wd
// One block per sequence row l. 384 threads (one per channel). All I/O fp32.
// ---------------------------------------------------------------------------
__global__ __launch_bounds__(384) void stage1_kernel(
    const float* __restrict__ act, const float* __restrict__ mask,
    const float* __restrict__ gamma, const float* __restrict__ beta,
    const float* __restrict__ Wl, const float* __restrict__ bl,
    const float* __restrict__ Wr, const float* __restrict__ br,
    const float* __restrict__ Wout, const float* __restrict__ bout,
    float* __restrict__ Ri, float* __restrict__ right_f,
    bf16* __restrict__ left_b) {
  const int l = blockIdx.x;
  const int tid = threadIdx.x;          // 0..383
  __shared__ float xs[C_IN];
  __shared__ float red[12];             // 6 waves x {sum, sumsq}
  __shared__ float partial[6][64];
  __shared__ float rrow[C_OUT];

  float a = act[l * C_IN + tid];
  // wave(64) reduction of sum / sumsq
  float s = a, s2 = a * a;
  #pragma unroll
  for (int off = 32; off; off >>= 1) {
    s += __shfl_down(s, off);
    s2 += __shfl_down(s2, off);
  }
  const int w = tid >> 6, lane = tid & 63;
  if (lane == 0) { red[w] = s; red[6 + w] = s2; }
  __syncthreads();
  float ts = 0.f, ts2 = 0.f;
  #pragma unroll
  for (int k = 0; k < 6; ++k) { ts += red[k]; ts2 += red[6 + k]; }
  const float mu = ts * (1.0f / C_IN);
  const float var = ts2 * (1.0f / C_IN) - mu * mu;
  const float rstd = rsqrtf(var + 1e-5f);
  const float x = (a - mu) * rstd * gamma[tid] + beta[tid];
  xs[tid] = x;
  __syncthreads();

  // projections: n = tid&63 (0..31 -> left col, 32..63 -> right col),
  // c-chunk = tid>>6 (6 chunks of 64)
  {
    const int n = tid & 63, chunk = tid >> 6;
    const float* W = (n < 32) ? Wl : Wr;
    const int nn = n & 31;
    float dot = 0.f;
    const int cbeg = chunk * 64;
    #pragma unroll 8
    for (int c = cbeg; c < cbeg + 64; ++c)
      dot += xs[c] * W[c * C_OUT + nn];
    partial[chunk][n] = dot;
  }
  __syncthreads();
  const float mval = mask[l];
  if (tid < 64) {
    float tot = 0.f;
    #pragma unroll
    for (int k = 0; k < 6; ++k) tot += partial[k][tid];
    if (tid < 32) {
      float v = mval * (tot + bl[tid]);
      left_b[l * C_OUT + tid] = f2b(v);
    } else {
      float v = mval * (tot + br[tid - 32]);
      right_f[l * C_OUT + (tid - 32)] = v;
      rrow[tid - 32] = v;
    }
  }
  __syncthreads();
  // Ri[l][d] = bout[d] - sum_n rrow[n] * Wd[n][d],  Wd = Wout rows 32..63
  if (tid < N_OUT) {
    float acc = bout[tid];
    #pragma unroll 8
    for (int n = 0; n < 32; ++n)
      acc -= rrow[n] * Wout[(32 + n) * N_OUT + tid];
    Ri[l * N_OUT + tid] = acc;
  }
}

// ---------------------------------------------------------------------------
// Stage 2: out[i, j, d] = left[j,:] @ (right[i,:]*Wp + Wd) + Ri[i,d]
// Grid: (6 j-tiles, 768 i). Block: 256 threads (4 waves).
// Each block: one i, 128 j, 128 d. MFMA 16x16x32 bf16. Output fp32.
// ---------------------------------------------------------------------------
__global__ __launch_bounds__(256) void stage2_kernel(
    const float* __restrict__ right_f, const bf16* __restrict__ left_b,
    const float* __restrict__ Ri, const float* __restrict__ Wout,
    float* __restrict__ out) {
  const int i = blockIdx.y;
  const int j_base = blockIdx.x * 128;
  const int tid = threadIdx.x;

  __shared__ bf16 wrpT[128][40];   // [d][c], row stride 40 bf16 = 80 B (16B-aligned)
  __shared__ float rsh[C_OUT];

  if (tid < C_OUT) rsh[tid] = right_f[i * C_OUT + tid];
  __syncthreads();
  {
    // B_i[c][d] = right[i,c]*Wp[c,d] + Wd[c,d], stored transposed as bf16
    const int d = tid & 127, c0 = (tid >> 7) * 16;
    #pragma unroll
    for (int c = c0; c < c0 + 16; ++c) {
      float wp = Wout[c * N_OUT + d];
      float wd = Wout[(c + 32) * N_OUT + d];
      wrpT[d][c] = f2b(rsh[c] * wp + wd);
    }
  }
  __syncthreads();

  const int w = tid >> 6, lane = tid & 63;
  const int quad = lane >> 4, l16 = lane & 15;

  // B fragments: bfr[t8][jj] = B_i[k=quad*8+jj][n = t8*16 + l16] (all waves same)
  short8 bfr[8];
  float riv[8];
  #pragma unroll
  for (int t8 = 0; t8 < 8; ++t8) {
    bfr[t8] = *(const short8*)&wrpT[t8 * 16 + l16][quad * 8];
    riv[t8] = Ri[i * N_OUT + t8 * 16 + l16];
  }

  // each wave: 2 j-subtiles of 16
  #pragma unroll
  for (int jt2 = 0; jt2 < 2; ++jt2) {
    const int j0 = j_base + w * 32 + jt2 * 16;
    // A fragment: A[m=l16][k=quad*8+jj] = left[j0+l16][quad*8+jj]
    short8 afr = *(const short8*)&left_b[(j0 + l16) * C_OUT + quad * 8];
    #pragma unroll
    for (int t8 = 0; t8 < 8; ++t8) {
      float4v acc = __builtin_amdgcn_mfma_f32_16x16x32_bf16(
          afr, bfr[t8], (float4v){0.f, 0.f, 0.f, 0.f}, 0, 0, 0);
      const int dd = t8 * 16 + l16;
      #pragma unroll
      for (int r = 0; r < 4; ++r) {
        const int j = j0 + quad * 4 + r;
        out[(i * L_SEQ + j) * N_OUT + dd] = acc[r] + riv[t8];
      }
    }
  }
}

extern "C" void kernel_launch(void* const* d_in, const int* in_sizes, int n_in,
                              void* d_out, int out_size, void* d_ws, size_t ws_size,
                              hipStream_t stream) {
  const float* act   = (const float*)d_in[0];
  const float* mask  = (const float*)d_in[1];
  const float* gamma = (const float*)d_in[2];
  const float* beta  = (const float*)d_in[3];
  const float* Wl    = (const float*)d_in[4];
  const float* bl    = (const float*)d_in[5];
  const float* Wr    = (const float*)d_in[6];
  const float* br    = (const float*)d_in[7];
  const float* Wout  = (const float*)d_in[8];
  const float* bout  = (const float*)d_in[9];
  float* out = (float*)d_out;

  // workspace layout
  float* Ri      = (float*)d_ws;                              // 768*128 f32 = 393216 B
  float* right_f = (float*)((char*)d_ws + 393216);            // 768*32  f32 =  98304 B
  bf16*  left_b  = (bf16*)((char*)d_ws + 393216 + 98304);     // 768*32  bf16 = 49152 B

  stage1_kernel<<<dim3(L_SEQ), dim3(C_IN), 0, stream>>>(
      act, mask, gamma, beta, Wl, bl, Wr, br, Wout, bout, Ri, right_f, left_b);

  stage2_kernel<<<dim3(6, L_SEQ), dim3(256), 0, stream>>>(
      right_f, left_b, Ri, Wout, out);
}

// Round 3
// 329.492 us; speedup vs baseline: 1.0257x; 1.0257x over previous
//
#include <hip/hip_runtime.h>
#include <hip/hip_bf16.h>

typedef __attribute__((ext_vector_type(8))) short short8;
typedef __attribute__((ext_vector_type(4))) float float4v;

#define L_SEQ 768
#define C_IN 384
#define C_OUT 32
#define N_OUT 128

using bf16 = __hip_bfloat16;

static __device__ inline bf16 f2b(float f) { return __float2bfloat16(f); }

// ---------------------------------------------------------------------------
// Stage 1: LayerNorm + left/right projections + Ri = b_out - right @ Wd
// One block per sequence row l. 384 threads (one per channel). All I/O fp32.
// ---------------------------------------------------------------------------
__global__ __launch_bounds__(384) void stage1_kernel(
    const float* __restrict__ act, const float* __restrict__ mask,
    const float* __restrict__ gamma, const float* __restrict__ beta,
    const float* __restrict__ Wl, const float* __restrict__ bl,
    const float* __restrict__ Wr, const float* __restrict__ br,
    const float* __restrict__ Wout, const float* __restrict__ bout,
    float* __restrict__ Ri, float* __restrict__ right_f,
    bf16* __restrict__ left_b) {
  const int l = blockIdx.x;
  const int tid = threadIdx.x;          // 0..383
  __shared__ float xs[C_IN];
  __shared__ float red[12];             // 6 waves x {sum, sumsq}
  __shared__ float partial[6][64];
  __shared__ float rrow[C_OUT];

  float a = act[l * C_IN + tid];
  float s = a, s2 = a * a;
  #pragma unroll
  for (int off = 32; off; off >>= 1) {
    s += __shfl_down(s, off);
    s2 += __shfl_down(s2, off);
  }
  const int w = tid >> 6, lane = tid & 63;
  if (lane == 0) { red[w] = s; red[6 + w] = s2; }
  __syncthreads();
  float ts = 0.f, ts2 = 0.f;
  #pragma unroll
  for (int k = 0; k < 6; ++k) { ts += red[k]; ts2 += red[6 + k]; }
  const float mu = ts * (1.0f / C_IN);
  const float var = ts2 * (1.0f / C_IN) - mu * mu;
  const float rstd = rsqrtf(var + 1e-5f);
  const float x = (a - mu) * rstd * gamma[tid] + beta[tid];
  xs[tid] = x;
  __syncthreads();

  {
    const int n = tid & 63, chunk = tid >> 6;
    const float* W = (n < 32) ? Wl : Wr;
    const int nn = n & 31;
    float dot = 0.f;
    const int cbeg = chunk * 64;
    #pragma unroll 8
    for (int c = cbeg; c < cbeg + 64; ++c)
      dot += xs[c] * W[c * C_OUT + nn];
    partial[chunk][n] = dot;
  }
  __syncthreads();
  const float mval = mask[l];
  if (tid < 64) {
    float tot = 0.f;
    #pragma unroll
    for (int k = 0; k < 6; ++k) tot += partial[k][tid];
    if (tid < 32) {
      float v = mval * (tot + bl[tid]);
      left_b[l * C_OUT + tid] = f2b(v);
    } else {
      float v = mval * (tot + br[tid - 32]);
      right_f[l * C_OUT + (tid - 32)] = v;
      rrow[tid - 32] = v;
    }
  }
  __syncthreads();
  if (tid < N_OUT) {
    float acc = bout[tid];
    #pragma unroll 8
    for (int n = 0; n < 32; ++n)
      acc -= rrow[n] * Wout[(32 + n) * N_OUT + tid];
    Ri[l * N_OUT + tid] = acc;
  }
}

// ---------------------------------------------------------------------------
// Stage 2: out[i, j, d] = left[j,:] @ (right[i,:]*Wp + Wd) + Ri[i,d]
// Grid: (6 j-tiles, 768 i). Block: 256 threads (4 waves).
// Each block: one i, 128 j, 128 d. MFMA 16x16x32 bf16. Output fp32.
// Epilogue: stage 64x128 fp32 tile in LDS, then linear float4 nontemporal
// copy — the block's output region is a contiguous 64 KB span (j before d).
// ---------------------------------------------------------------------------
#define OT_STRIDE 132   // fp32 elements per j-row in LDS tile (16B-aligned, 2-way bank max)

__global__ __launch_bounds__(256) void stage2_kernel(
    const float* __restrict__ right_f, const bf16* __restrict__ left_b,
    const float* __restrict__ Ri, const float* __restrict__ Wout,
    float* __restrict__ out) {
  const int i = blockIdx.y;
  const int j_base = blockIdx.x * 128;
  const int tid = threadIdx.x;

  __shared__ bf16 wrpT[128][40];       // B_i^T [d][c], row 80 B (16B-aligned)
  __shared__ float rsh[C_OUT];
  __shared__ float otile[64 * OT_STRIDE];  // one 64-row j-group of the output tile

  if (tid < C_OUT) rsh[tid] = right_f[i * C_OUT + tid];
  __syncthreads();
  {
    // B_i[c][d] = right[i,c]*Wp[c,d] + Wd[c,d], stored transposed as bf16
    const int d = tid & 127, c0 = (tid >> 7) * 16;
    #pragma unroll
    for (int c = c0; c < c0 + 16; ++c) {
      float wp = Wout[c * N_OUT + d];
      float wd = Wout[(c + 32) * N_OUT + d];
      wrpT[d][c] = f2b(rsh[c] * wp + wd);
    }
  }
  __syncthreads();

  const int w = tid >> 6, lane = tid & 63;
  const int quad = lane >> 4, l16 = lane & 15;

  // B fragments: bfr[t8][jj] = B_i[k=quad*8+jj][n = t8*16 + l16] (all waves same)
  short8 bfr[8];
  float riv[8];
  #pragma unroll
  for (int t8 = 0; t8 < 8; ++t8) {
    bfr[t8] = *(const short8*)&wrpT[t8 * 16 + l16][quad * 8];
    riv[t8] = Ri[i * N_OUT + t8 * 16 + l16];
  }

  // two rounds of 64 contiguous j rows each
  #pragma unroll 1
  for (int round = 0; round < 2; ++round) {
    const int jg = round * 64;                 // j-group base (local)
    const int j0l = w * 16;                    // wave's 16 rows within group
    // A fragment: A[m=l16][k=quad*8+jj] = left[j_base+jg+j0l+l16][quad*8+jj]
    short8 afr = *(const short8*)&left_b[(j_base + jg + j0l + l16) * C_OUT + quad * 8];
    #pragma unroll
    for (int t8 = 0; t8 < 8; ++t8) {
      float4v acc = __builtin_amdgcn_mfma_f32_16x16x32_bf16(
          afr, bfr[t8], (float4v){0.f, 0.f, 0.f, 0.f}, 0, 0, 0);
      const int dd = t8 * 16 + l16;
      #pragma unroll
      for (int r = 0; r < 4; ++r)
        otile[(j0l + quad * 4 + r) * OT_STRIDE + dd] = acc[r] + riv[t8];
    }
    __syncthreads();
    // linear coalesced copy: 64 rows x 128 d = 32 KB
    float* outp = out + (size_t)(i * L_SEQ + j_base + jg) * N_OUT;
    #pragma unroll
    for (int it = 0; it < 8; ++it) {
      const int g = (it * 256 + tid) * 4;      // dword offset in tile, float4 step
      const int jj = g >> 7, dd = g & 127;
      float4v v = *(const float4v*)&otile[jj * OT_STRIDE + dd];
      __builtin_nontemporal_store(v, (float4v*)&outp[g]);
    }
    __syncthreads();
  }
}

extern "C" void kernel_launch(void* const* d_in, const int* in_sizes, int n_in,
                              void* d_out, int out_size, void* d_ws, size_t ws_size,
                              hipStream_t stream) {
  const float* act   = (const float*)d_in[0];
  const float* mask  = (const float*)d_in[1];
  const float* gamma = (const float*)d_in[2];
  const float* beta  = (const float*)d_in[3];
  const float* Wl    = (const float*)d_in[4];
  const float* bl    = (const float*)d_in[5];
  const float* Wr    = (const float*)d_in[6];
  const float* br    = (const float*)d_in[7];
  const float* Wout  = (const float*)d_in[8];
  const float* bout  = (const float*)d_in[9];
  float* out = (float*)d_out;

  float* Ri      = (float*)d_ws;                              // 768*128 f32
  float* right_f = (float*)((char*)d_ws + 393216);            // 768*32  f32
  bf16*  left_b  = (bf16*)((char*)d_ws + 393216 + 98304);     // 768*32  bf16

  stage1_kernel<<<dim3(L_SEQ), dim3(C_IN), 0, stream>>>(
      act, mask, gamma, beta, Wl, bl, Wr, br, Wout, bout, Ri, right_f, left_b);

  stage2_kernel<<<dim3(6, L_SEQ), dim3(256), 0, stream>>>(
      right_f, left_b, Ri, Wout, out);
}